// Round 5
// baseline (243.566 us; speedup 1.0000x reference)
//
#include <hip/hip_runtime.h>
#include <math.h>

// Problem constants (fixed by the reference)
#define T_    1024      // B*S tokens
#define H_    512       // hidden
#define I_    1024      // intermediate
#define E_    64        // routed experts
#define K_    4         // top-k
#define NPAIR (T_*K_)   // 4096 routed (token,slot) pairs
#define NENT  (NPAIR + T_)  // + shared-expert entries at [NPAIR + t]

#define BM 128          // rows per work block
#define BN 64
#define BKS 64          // k-step (elements)
#define LDP 72          // padded LDS row (elements): 144B stride -> 2-way max
#define MAXWORK 160     // worst-case row-blocks
#define NT1 (H_/BKS)    // 8
#define NT2 (I_/BKS)    // 16

typedef float  f32x4  __attribute__((ext_vector_type(4)));
typedef uint   u32x4  __attribute__((ext_vector_type(4)));
typedef short  bf16x8 __attribute__((ext_vector_type(8)));

// Raw barrier WITHOUT the __syncthreads() vmcnt(0) drain: LDS ops flushed,
// outstanding global loads stay in flight across the barrier.
#define BARRIER() asm volatile("s_waitcnt lgkmcnt(0)\n\ts_barrier" ::: "memory")
// Pin: force the register to hold the loaded (fp32/raw) data at this point.
// Blocks the compiler from sinking conversions up to the load site (which
// would re-insert the vmcnt wait at issue time and kill the prefetch).
#define PIN(v) asm volatile("" : "+v"(v))

__device__ __forceinline__ ushort f2bf(float f) {
    uint u = __float_as_uint(f);
    u += 0x7fffu + ((u >> 16) & 1u);   // round-to-nearest-even
    return (ushort)(u >> 16);
}
__device__ __forceinline__ ushort4 cvt4(f32x4 v) {
    return make_ushort4(f2bf(v[0]), f2bf(v[1]), f2bf(v[2]), f2bf(v[3]));
}

// ---------------------------------------------------------------------------
// Router: one 64-thread block per token.
// ---------------------------------------------------------------------------
__global__ __launch_bounds__(64) void moe_router(
    const float* __restrict__ x, const float* __restrict__ rw,
    const float* __restrict__ rb, const float* __restrict__ eb,
    int* __restrict__ idx_out, float* __restrict__ gate_out)
{
    const int t = blockIdx.x;
    const int lane = threadIdx.x;  // 0..63
    __shared__ float xs[H_];
    __shared__ float lg[E_];
    __shared__ float bs[E_];
    for (int i = lane; i < H_; i += 64) xs[i] = x[(size_t)t*H_ + i];
    bs[lane] = eb[lane];
    __syncthreads();
    float acc = 0.f;
    const float* wrow = rw + (size_t)lane*H_;
    for (int k = 0; k < H_; k += 4) {
        float4 w4 = *reinterpret_cast<const float4*>(wrow + k);
        acc = fmaf(xs[k+0], w4.x, acc);
        acc = fmaf(xs[k+1], w4.y, acc);
        acc = fmaf(xs[k+2], w4.z, acc);
        acc = fmaf(xs[k+3], w4.w, acc);
    }
    lg[lane] = acc + rb[lane];
    __syncthreads();
    if (lane == 0) {
        unsigned long long used = 0ull;
        int sel[K_]; float orig[K_];
        for (int k = 0; k < K_; ++k) {
            float best = -INFINITY; int bi = 0;
            for (int e = 0; e < E_; ++e) {
                if (used & (1ull << e)) continue;
                float v = lg[e] + bs[e];
                if (v > best) { best = v; bi = e; }   // strict > : lowest idx on tie
            }
            used |= (1ull << bi);
            sel[k] = bi; orig[k] = lg[bi];
        }
        float s[K_]; float sum = 0.f;
        for (int k = 0; k < K_; ++k) { s[k] = 1.f/(1.f + __expf(-orig[k])); sum += s[k]; }
        sum = fmaxf(sum, 1e-12f);
        for (int k = 0; k < K_; ++k) {
            idx_out[t*K_ + k] = sel[k];
            gate_out[t*K_ + k] = s[k] / sum;
        }
    }
}

// ---------------------------------------------------------------------------
// Build per-expert token lists + flattened row-block work list (single block).
// ---------------------------------------------------------------------------
__global__ __launch_bounds__(256) void moe_build(
    const int* __restrict__ idx, const float* __restrict__ gates,
    int* __restrict__ cnts, int* __restrict__ offs,
    int* __restrict__ entry_token, float* __restrict__ entry_gate,
    int* __restrict__ pair_pos,
    int* __restrict__ blk_e, int* __restrict__ blk_ro, int* __restrict__ nwork)
{
    __shared__ int c[E_];
    __shared__ int run[E_];
    const int tid = threadIdx.x;
    if (tid < E_) c[tid] = 0;
    __syncthreads();
    for (int p = tid; p < NPAIR; p += 256) atomicAdd(&c[idx[p]], 1);
    __syncthreads();
    if (tid == 0) {
        int o = 0;
        for (int e = 0; e < E_; ++e) { run[e] = o; offs[e] = o; cnts[e] = c[e]; o += c[e]; }
        offs[E_] = NPAIR;   // shared-expert entries
        cnts[E_] = T_;
        int nb = 0;
        for (int e = 0; e <= E_; ++e) {
            int n = (e < E_) ? c[e] : T_;
            for (int ro = 0; ro < n; ro += BM) { blk_e[nb] = e; blk_ro[nb] = ro; ++nb; }
        }
        nwork[0] = nb;
    }
    __syncthreads();
    for (int p = tid; p < NPAIR; p += 256) {
        int e = idx[p];
        int pos = atomicAdd(&run[e], 1);
        entry_token[pos] = p / K_;
        entry_gate[pos]  = gates[p];
        pair_pos[p]      = pos;
    }
    for (int t = tid; t < T_; t += 256) {
        entry_token[NPAIR + t] = t;
        entry_gate[NPAIR + t]  = 1.0f;
    }
}

// ---------------------------------------------------------------------------
// Stage 1: h1 = silu(X w1^T + b1) * (X w3^T + b3) -> bf16
// 512 thr = 8 waves. 2-iteration-deep register prefetch, pinned registers,
// one raw barrier per K-step, LDS double-buffer.
// ---------------------------------------------------------------------------
__global__ __launch_bounds__(512, 4) void moe_stage1(
    const float* __restrict__ x,
    const float* __restrict__ w1, const float* __restrict__ b1,
    const float* __restrict__ w3, const float* __restrict__ b3,
    const float* __restrict__ sw1, const float* __restrict__ sb1,
    const float* __restrict__ sw3, const float* __restrict__ sb3,
    const int* __restrict__ cnts, const int* __restrict__ offs,
    const int* __restrict__ entry_token,
    const int* __restrict__ blk_e, const int* __restrict__ blk_ro,
    const int* __restrict__ nwork,
    ushort* __restrict__ h1buf)
{
    const int w = blockIdx.x;
    if (w >= nwork[0]) return;
    const int e  = blk_e[w];
    const int ro = blk_ro[w];
    const int itile = blockIdx.y;   // 0..I_/BN-1
    const int n = cnts[e];
    const int off = offs[e];
    const int rows = min(BM, n - ro);
    const float* W1 = (e < E_) ? (w1 + (size_t)e*I_*H_) : sw1;
    const float* W3 = (e < E_) ? (w3 + (size_t)e*I_*H_) : sw3;
    const float* B1 = (e < E_) ? (b1 + (size_t)e*I_) : sb1;
    const float* B3 = (e < E_) ? (b3 + (size_t)e*I_) : sb3;

    __shared__ ushort Xs [2][BM][LDP];   // 36864 B
    __shared__ ushort W1s[2][BN][LDP];   // 18432 B
    __shared__ ushort W3s[2][BN][LDP];   // 18432 B  -> 72 KB total

    const int tid  = threadIdx.x;
    const int lane = tid & 63;
    const int wid  = tid >> 6;          // 0..7
    const int wm   = wid >> 1;          // 0..3
    const int wn   = wid & 1;           // 0..1
    const int l15  = lane & 15;
    const int lg   = lane >> 4;         // 0..3

    const int sr = tid >> 4;            // staging row base 0..31
    const int sc = tid & 15;            // 16B column chunk 0..15

    // K-invariant row pointers. Rows beyond 'rows' read a neighboring valid
    // entry (all NENT entries initialized); garbage lands only in masked rows.
    const float* xp[4];
    #pragma unroll
    for (int i = 0; i < 4; ++i)
        xp[i] = x + (size_t)entry_token[off + ro + sr + i*32]*H_ + sc*4;
    const float* wp[2];
    #pragma unroll
    for (int i = 0; i < 2; ++i)
        wp[i] = W1 + (size_t)(itile*BN + sr + i*32)*H_ + sc*4;
    const ptrdiff_t d31 = (const float*)W3 - (const float*)W1;

    f32x4 acc1[2][2] = {};
    f32x4 acc3[2][2] = {};

    f32x4 SA[8], SB[8];   // two named prefetch sets (static indexing only)

    auto issue = [&](f32x4* R, int tile) {
        const int kc = tile * BKS;
        #pragma unroll
        for (int i = 0; i < 4; ++i) R[i] = *reinterpret_cast<const f32x4*>(xp[i] + kc);
        #pragma unroll
        for (int i = 0; i < 2; ++i) {
            R[4+i] = *reinterpret_cast<const f32x4*>(wp[i] + kc);
            R[6+i] = *reinterpret_cast<const f32x4*>(wp[i] + kc + d31);
        }
    };
    auto cvtwrite = [&](f32x4* R, int b) {
        #pragma unroll
        for (int i = 0; i < 8; ++i) PIN(R[i]);   // keep fp32 data until HERE
        #pragma unroll
        for (int i = 0; i < 4; ++i)
            *reinterpret_cast<ushort4*>(&Xs[b][sr + i*32][sc*4]) = cvt4(R[i]);
        #pragma unroll
        for (int i = 0; i < 2; ++i) {
            *reinterpret_cast<ushort4*>(&W1s[b][sr + i*32][sc*4]) = cvt4(R[4+i]);
            *reinterpret_cast<ushort4*>(&W3s[b][sr + i*32][sc*4]) = cvt4(R[6+i]);
        }
    };
    auto mfma_step = [&](int b) {
        #pragma unroll
        for (int s = 0; s < 2; ++s) {
            bf16x8 a[2], bb1[2], bb3[2];
            #pragma unroll
            for (int f = 0; f < 2; ++f) {
                a[f]   = *reinterpret_cast<const bf16x8*>(&Xs [b][wm*32 + f*16 + l15][s*32 + lg*8]);
                bb1[f] = *reinterpret_cast<const bf16x8*>(&W1s[b][wn*32 + f*16 + l15][s*32 + lg*8]);
                bb3[f] = *reinterpret_cast<const bf16x8*>(&W3s[b][wn*32 + f*16 + l15][s*32 + lg*8]);
            }
            #pragma unroll
            for (int fm = 0; fm < 2; ++fm) {
                #pragma unroll
                for (int fn = 0; fn < 2; ++fn) {
                    acc1[fm][fn] = __builtin_amdgcn_mfma_f32_16x16x32_bf16(a[fm], bb1[fn], acc1[fm][fn], 0, 0, 0);
                    acc3[fm][fn] = __builtin_amdgcn_mfma_f32_16x16x32_bf16(a[fm], bb3[fn], acc3[fm][fn], 0, 0, 0);
                }
            }
        }
    };

    // prologue: tiles 0,1,2 in flight; stage tile 0
    issue(SA, 0);               // tile 0 (even -> SA)
    issue(SB, 1);               // tile 1 (odd  -> SB)
    cvtwrite(SA, 0);            // waits SA only (counted); SB stays in flight
    issue(SA, 2);               // tile 2
    BARRIER();

    #pragma unroll
    for (int tt = 0; tt < NT1; tt += 2) {
        // iter tt (even): compute buf0; stage tile tt+1 from SB; issue tt+3
        mfma_step(0);
        if (tt + 1 < NT1) {
            cvtwrite(SB, 1);
            if (tt + 3 < NT1) issue(SB, tt + 3);
        }
        BARRIER();
        // iter tt+1 (odd): compute buf1; stage tile tt+2 from SA; issue tt+4
        mfma_step(1);
        if (tt + 2 < NT1) {
            cvtwrite(SA, 0);
            if (tt + 4 < NT1) issue(SA, tt + 4);
        }
        BARRIER();
    }

    // epilogue: silu(z1)*z3 -> bf16
    #pragma unroll
    for (int fm = 0; fm < 2; ++fm) {
        #pragma unroll
        for (int fn = 0; fn < 2; ++fn) {
            const int col = itile*BN + wn*32 + fn*16 + l15;
            const float bv1 = B1[col];
            const float bv3 = B3[col];
            #pragma unroll
            for (int j = 0; j < 4; ++j) {
                const int rl = wm*32 + fm*16 + lg*4 + j;   // C/D: row=(lane>>4)*4+reg, col=lane&15
                if (rl < rows) {
                    float z1 = acc1[fm][fn][j] + bv1;
                    float z3 = acc3[fm][fn][j] + bv3;
                    float h = z1 / (1.f + __expf(-z1)) * z3;
                    h1buf[(size_t)(off+ro+rl)*I_ + col] = f2bf(h);
                }
            }
        }
    }
}

// ---------------------------------------------------------------------------
// Stage 2: y = gate * (h1 @ w2^T + b2) -> fp32. Same pipeline template.
// ---------------------------------------------------------------------------
__global__ __launch_bounds__(512, 4) void moe_stage2(
    const ushort* __restrict__ h1buf,
    const float* __restrict__ w2, const float* __restrict__ b2,
    const float* __restrict__ sw2, const float* __restrict__ sb2,
    const int* __restrict__ cnts, const int* __restrict__ offs,
    const float* __restrict__ entry_gate,
    const int* __restrict__ blk_e, const int* __restrict__ blk_ro,
    const int* __restrict__ nwork,
    float* __restrict__ ybuf)
{
    const int w = blockIdx.x;
    if (w >= nwork[0]) return;
    const int e  = blk_e[w];
    const int ro = blk_ro[w];
    const int htile = blockIdx.y;   // 0..H_/BN-1
    const int n = cnts[e];
    const int off = offs[e];
    const int rows = min(BM, n - ro);
    const float* W2 = (e < E_) ? (w2 + (size_t)e*H_*I_) : sw2;
    const float* B2 = (e < E_) ? (b2 + (size_t)e*H_) : sb2;

    __shared__ ushort Hs[2][BM][LDP];    // 36864 B
    __shared__ ushort Ws[2][BN][LDP];    // 18432 B -> 55.3 KB

    const int tid  = threadIdx.x;
    const int lane = tid & 63;
    const int wid  = tid >> 6;          // 0..7
    const int wm   = wid >> 1;
    const int wn   = wid & 1;
    const int l15  = lane & 15;
    const int lg   = lane >> 4;

    const int sr = tid >> 4;            // 0..31 (weight staging)
    const int sc = tid & 15;
    const int hr = tid >> 3;            // 0..63 (h1 staging)
    const int hc = tid & 7;

    const ushort* hp[2];
    #pragma unroll
    for (int i = 0; i < 2; ++i)
        hp[i] = h1buf + (size_t)(off + ro + hr + i*64)*I_ + hc*8;
    const float* wp[2];
    #pragma unroll
    for (int i = 0; i < 2; ++i)
        wp[i] = W2 + (size_t)(htile*BN + sr + i*32)*I_ + sc*4;

    f32x4 acc[2][2] = {};

    u32x4 HA[2], HB[2];
    f32x4 WA[2], WB[2];

    auto issue = [&](u32x4* HR, f32x4* WR, int tile) {
        const int kc = tile * BKS;
        #pragma unroll
        for (int i = 0; i < 2; ++i) {
            HR[i] = *reinterpret_cast<const u32x4*>(hp[i] + kc);
            WR[i] = *reinterpret_cast<const f32x4*>(wp[i] + kc);
        }
    };
    auto stwrite = [&](u32x4* HR, f32x4* WR, int b) {
        #pragma unroll
        for (int i = 0; i < 2; ++i) { PIN(HR[i]); PIN(WR[i]); }
        #pragma unroll
        for (int i = 0; i < 2; ++i) {
            *reinterpret_cast<u32x4*>(&Hs[b][hr + i*64][hc*8]) = HR[i];
            *reinterpret_cast<ushort4*>(&Ws[b][sr + i*32][sc*4]) = cvt4(WR[i]);
        }
    };
    auto mfma_step = [&](int b) {
        #pragma unroll
        for (int s = 0; s < 2; ++s) {
            bf16x8 a[2], bb[2];
            #pragma unroll
            for (int f = 0; f < 2; ++f) {
                a[f]  = *reinterpret_cast<const bf16x8*>(&Hs[b][wm*32 + f*16 + l15][s*32 + lg*8]);
                bb[f] = *reinterpret_cast<const bf16x8*>(&Ws[b][wn*32 + f*16 + l15][s*32 + lg*8]);
            }
            #pragma unroll
            for (int fm = 0; fm < 2; ++fm) {
                #pragma unroll
                for (int fn = 0; fn < 2; ++fn) {
                    acc[fm][fn] = __builtin_amdgcn_mfma_f32_16x16x32_bf16(a[fm], bb[fn], acc[fm][fn], 0, 0, 0);
                }
            }
        }
    };

    issue(HA, WA, 0);
    issue(HB, WB, 1);
    stwrite(HA, WA, 0);
    issue(HA, WA, 2);
    BARRIER();

    #pragma unroll
    for (int tt = 0; tt < NT2; tt += 2) {
        mfma_step(0);
        if (tt + 1 < NT2) {
            stwrite(HB, WB, 1);
            if (tt + 3 < NT2) issue(HB, WB, tt + 3);
        }
        BARRIER();
        mfma_step(1);
        if (tt + 2 < NT2) {
            stwrite(HA, WA, 0);
            if (tt + 4 < NT2) issue(HA, WA, tt + 4);
        }
        BARRIER();
    }

    #pragma unroll
    for (int fm = 0; fm < 2; ++fm) {
        #pragma unroll
        for (int fn = 0; fn < 2; ++fn) {
            const int col = htile*BN + wn*32 + fn*16 + l15;
            const float bv = B2[col];
            #pragma unroll
            for (int j = 0; j < 4; ++j) {
                const int rl = wm*32 + fm*16 + lg*4 + j;
                if (rl < rows) {
                    const float g = entry_gate[off + ro + rl];
                    ybuf[(size_t)(off+ro+rl)*H_ + col] = (acc[fm][fn][j] + bv) * g;
                }
            }
        }
    }
}

// ---------------------------------------------------------------------------
// Combine: out[t] = y_shared[t] + sum_k y_routed[pair_pos[t,k]]
// ---------------------------------------------------------------------------
__global__ __launch_bounds__(128) void moe_combine(
    const float* __restrict__ ybuf, const int* __restrict__ pair_pos,
    float* __restrict__ out)
{
    const int t = blockIdx.x;
    const int lane = threadIdx.x;     // 128 threads * 4 floats = 512
    const int h = lane * 4;
    const int p0 = pair_pos[t*K_+0], p1 = pair_pos[t*K_+1];
    const int p2 = pair_pos[t*K_+2], p3 = pair_pos[t*K_+3];
    float4 a  = *reinterpret_cast<const float4*>(ybuf + (size_t)(NPAIR+t)*H_ + h);
    float4 v0 = *reinterpret_cast<const float4*>(ybuf + (size_t)p0*H_ + h);
    float4 v1 = *reinterpret_cast<const float4*>(ybuf + (size_t)p1*H_ + h);
    float4 v2 = *reinterpret_cast<const float4*>(ybuf + (size_t)p2*H_ + h);
    float4 v3 = *reinterpret_cast<const float4*>(ybuf + (size_t)p3*H_ + h);
    float4 r;
    r.x = a.x + v0.x + v1.x + v2.x + v3.x;
    r.y = a.y + v0.y + v1.y + v2.y + v3.y;
    r.z = a.z + v0.z + v1.z + v2.z + v3.z;
    r.w = a.w + v0.w + v1.w + v2.w + v3.w;
    *reinterpret_cast<float4*>(out + (size_t)t*H_ + h) = r;
}

extern "C" void kernel_launch(void* const* d_in, const int* in_sizes, int n_in,
                              void* d_out, int out_size, void* d_ws, size_t ws_size,
                              hipStream_t stream)
{
    const float* x   = (const float*)d_in[0];
    const float* rw  = (const float*)d_in[1];
    const float* rb  = (const float*)d_in[2];
    const float* eb  = (const float*)d_in[3];
    const float* sw1 = (const float*)d_in[4];
    const float* sb1 = (const float*)d_in[5];
    const float* sw2 = (const float*)d_in[6];
    const float* sb2 = (const float*)d_in[7];
    const float* sw3 = (const float*)d_in[8];
    const float* sb3 = (const float*)d_in[9];
    const float* w1  = (const float*)d_in[10];
    const float* b1  = (const float*)d_in[11];
    const float* w2  = (const float*)d_in[12];
    const float* b2  = (const float*)d_in[13];
    const float* w3  = (const float*)d_in[14];
    const float* b3  = (const float*)d_in[15];
    float* out = (float*)d_out;

    char* p = (char*)d_ws;
    auto take = [&](size_t bytes) { char* q = p; p += (bytes + 255) & ~(size_t)255; return q; };
    int*    idxb  = (int*)   take((size_t)NPAIR*4);
    float*  gateb = (float*) take((size_t)NPAIR*4);
    int*    cnts  = (int*)   take((E_+1)*4);
    int*    offs  = (int*)   take((E_+1)*4);
    int*    etok  = (int*)   take((size_t)NENT*4);
    float*  egate = (float*) take((size_t)NENT*4);
    int*    ppos  = (int*)   take((size_t)NPAIR*4);
    int*    blk_e = (int*)   take((size_t)MAXWORK*4);
    int*    blk_ro= (int*)   take((size_t)MAXWORK*4);
    int*    nwork = (int*)   take(4);
    ushort* h1buf = (ushort*)take((size_t)NENT*I_*2);
    float*  ybuf  = (float*) take((size_t)NENT*H_*4);

    moe_router <<<T_, 64, 0, stream>>>(x, rw, rb, eb, idxb, gateb);
    moe_build  <<<1, 256, 0, stream>>>(idxb, gateb, cnts, offs, etok, egate, ppos,
                                       blk_e, blk_ro, nwork);
    moe_stage1 <<<dim3(MAXWORK, I_/BN), 512, 0, stream>>>(x, w1, b1, w3, b3,
                                                          sw1, sb1, sw3, sb3,
                                                          cnts, offs, etok,
                                                          blk_e, blk_ro, nwork, h1buf);
    moe_stage2 <<<dim3(MAXWORK, H_/BN), 512, 0, stream>>>(h1buf, w2, b2, sw2, sb2,
                                                          cnts, offs, egate,
                                                          blk_e, blk_ro, nwork, ybuf);
    moe_combine<<<T_, 128, 0, stream>>>(ybuf, ppos, out);
}

// Round 6
// 201.670 us; speedup vs baseline: 1.2077x; 1.2077x over previous
//
#include <hip/hip_runtime.h>
#include <math.h>

// Problem constants (fixed by the reference)
#define T_    1024      // B*S tokens
#define H_    512       // hidden
#define I_    1024      // intermediate
#define E_    64        // routed experts
#define K_    4         // top-k
#define NPAIR (T_*K_)   // 4096 routed (token,slot) pairs
#define NENT  (NPAIR + T_)  // + shared-expert entries at [NPAIR + t]

#define BM 128          // rows per work block
#define BN 64           // output cols per block (I- or H-tile)
#define BKS 64          // k-step (elements)
#define MAXWORK 160
#define NT1 (H_/BKS)    // 8
#define NT2 (I_/BKS)    // 16

typedef float  f32x4  __attribute__((ext_vector_type(4)));
typedef short  bf16x8 __attribute__((ext_vector_type(8)));

__device__ __forceinline__ ushort f2bf(float f) {
    uint u = __float_as_uint(f);
    u += 0x7fffu + ((u >> 16) & 1u);   // round-to-nearest-even
    return (ushort)(u >> 16);
}
__device__ __forceinline__ bf16x8 cvt8(f32x4 a, f32x4 b) {
    bf16x8 r;
    r[0] = (short)f2bf(a[0]); r[1] = (short)f2bf(a[1]);
    r[2] = (short)f2bf(a[2]); r[3] = (short)f2bf(a[3]);
    r[4] = (short)f2bf(b[0]); r[5] = (short)f2bf(b[1]);
    r[6] = (short)f2bf(b[2]); r[7] = (short)f2bf(b[3]);
    return r;
}

// async global->LDS, 16B per lane; LDS dest = wave-uniform base + lane*16
__device__ __forceinline__ void gload16(const void* g, void* lds) {
    __builtin_amdgcn_global_load_lds(
        (const __attribute__((address_space(1))) unsigned int*)g,
        (__attribute__((address_space(3))) unsigned int*)lds, 16, 0, 0);
}

// ---------------------------------------------------------------------------
// x -> bf16 pre-pass (2 MB, ~2 us)
// ---------------------------------------------------------------------------
__global__ __launch_bounds__(256) void x_cvt(const float* __restrict__ x,
                                             ushort* __restrict__ xb)
{
    const int i = blockIdx.x*256 + threadIdx.x;     // T_*H_/4 float4s
    float4 v = reinterpret_cast<const float4*>(x)[i];
    reinterpret_cast<ushort4*>(xb)[i] =
        make_ushort4(f2bf(v.x), f2bf(v.y), f2bf(v.z), f2bf(v.w));
}

// ---------------------------------------------------------------------------
// Router: one 64-thread block per token.
// ---------------------------------------------------------------------------
__global__ __launch_bounds__(64) void moe_router(
    const float* __restrict__ x, const float* __restrict__ rw,
    const float* __restrict__ rb, const float* __restrict__ eb,
    int* __restrict__ idx_out, float* __restrict__ gate_out)
{
    const int t = blockIdx.x;
    const int lane = threadIdx.x;  // 0..63
    __shared__ float xs[H_];
    __shared__ float lg[E_];
    __shared__ float bs[E_];
    for (int i = lane; i < H_; i += 64) xs[i] = x[(size_t)t*H_ + i];
    bs[lane] = eb[lane];
    __syncthreads();
    float acc = 0.f;
    const float* wrow = rw + (size_t)lane*H_;
    for (int k = 0; k < H_; k += 4) {
        float4 w4 = *reinterpret_cast<const float4*>(wrow + k);
        acc = fmaf(xs[k+0], w4.x, acc);
        acc = fmaf(xs[k+1], w4.y, acc);
        acc = fmaf(xs[k+2], w4.z, acc);
        acc = fmaf(xs[k+3], w4.w, acc);
    }
    lg[lane] = acc + rb[lane];
    __syncthreads();
    if (lane == 0) {
        unsigned long long used = 0ull;
        int sel[K_]; float orig[K_];
        for (int k = 0; k < K_; ++k) {
            float best = -INFINITY; int bi = 0;
            for (int e = 0; e < E_; ++e) {
                if (used & (1ull << e)) continue;
                float v = lg[e] + bs[e];
                if (v > best) { best = v; bi = e; }   // strict > : lowest idx on tie
            }
            used |= (1ull << bi);
            sel[k] = bi; orig[k] = lg[bi];
        }
        float s[K_]; float sum = 0.f;
        for (int k = 0; k < K_; ++k) { s[k] = 1.f/(1.f + __expf(-orig[k])); sum += s[k]; }
        sum = fmaxf(sum, 1e-12f);
        for (int k = 0; k < K_; ++k) {
            idx_out[t*K_ + k] = sel[k];
            gate_out[t*K_ + k] = s[k] / sum;
        }
    }
}

// ---------------------------------------------------------------------------
// Build per-expert token lists + flattened row-block work list (single block).
// ---------------------------------------------------------------------------
__global__ __launch_bounds__(256) void moe_build(
    const int* __restrict__ idx, const float* __restrict__ gates,
    int* __restrict__ cnts, int* __restrict__ offs,
    int* __restrict__ entry_token, float* __restrict__ entry_gate,
    int* __restrict__ pair_pos,
    int* __restrict__ blk_e, int* __restrict__ blk_ro, int* __restrict__ nwork)
{
    __shared__ int c[E_];
    __shared__ int run[E_];
    const int tid = threadIdx.x;
    if (tid < E_) c[tid] = 0;
    __syncthreads();
    for (int p = tid; p < NPAIR; p += 256) atomicAdd(&c[idx[p]], 1);
    __syncthreads();
    if (tid == 0) {
        int o = 0;
        for (int e = 0; e < E_; ++e) { run[e] = o; offs[e] = o; cnts[e] = c[e]; o += c[e]; }
        offs[E_] = NPAIR;   // shared-expert entries
        cnts[E_] = T_;
        int nb = 0;
        for (int e = 0; e <= E_; ++e) {
            int n = (e < E_) ? c[e] : T_;
            for (int ro = 0; ro < n; ro += BM) { blk_e[nb] = e; blk_ro[nb] = ro; ++nb; }
        }
        nwork[0] = nb;
    }
    __syncthreads();
    for (int p = tid; p < NPAIR; p += 256) {
        int e = idx[p];
        int pos = atomicAdd(&run[e], 1);
        entry_token[pos] = p / K_;
        entry_gate[pos]  = gates[p];
        pair_pos[p]      = pos;
    }
    for (int t = tid; t < T_; t += 256) {
        entry_token[NPAIR + t] = t;
        entry_gate[NPAIR + t]  = 1.0f;
    }
}

// ---------------------------------------------------------------------------
// Stage 1: h1 = silu(X w1^T + b1) * (X w3^T + b3) -> bf16
// m97 structure: 256 thr (4 waves, 2x2 of 64x32), single-buffered LDS via
// global_load_lds, 2 barriers/K-step, 48 KB LDS -> 3 blocks/CU.
// X bf16 [128][64] (16B-chunk XOR swizzle); W1/W3 fp32 [64][64] (32B-chunk
// XOR swizzle), converted bf16 at fragment read. Rule-21: linear LDS dest,
// pre-swizzled global source, swizzled read (same involution).
// ---------------------------------------------------------------------------
__global__ __launch_bounds__(256, 3) void moe_stage1(
    const ushort* __restrict__ xbf,
    const float* __restrict__ w1, const float* __restrict__ b1,
    const float* __restrict__ w3, const float* __restrict__ b3,
    const float* __restrict__ sw1, const float* __restrict__ sb1,
    const float* __restrict__ sw3, const float* __restrict__ sb3,
    const int* __restrict__ cnts, const int* __restrict__ offs,
    const int* __restrict__ entry_token,
    const int* __restrict__ blk_e, const int* __restrict__ blk_ro,
    const int* __restrict__ nwork,
    ushort* __restrict__ h1buf)
{
    const int w = blockIdx.x;
    if (w >= nwork[0]) return;
    const int e  = blk_e[w];
    const int ro = blk_ro[w];
    const int itile = blockIdx.y;   // 0..I_/BN-1
    const int n = cnts[e];
    const int off = offs[e];
    const int rows = min(BM, n - ro);
    const float* W1 = (e < E_) ? (w1 + (size_t)e*I_*H_) : sw1;
    const float* W3 = (e < E_) ? (w3 + (size_t)e*I_*H_) : sw3;
    const float* B1 = (e < E_) ? (b1 + (size_t)e*I_) : sb1;
    const float* B3 = (e < E_) ? (b3 + (size_t)e*I_) : sb3;

    __shared__ __align__(16) ushort XL [BM*BKS];   // 16 KB
    __shared__ __align__(16) float  W1L[BN*BKS];   // 16 KB
    __shared__ __align__(16) float  W3L[BN*BKS];   // 16 KB

    const int tid  = threadIdx.x;
    const int lane = tid & 63;
    const int wid  = tid >> 6;          // 0..3
    const int wm   = wid >> 1;          // 0..1 -> 64 rows
    const int wn   = wid & 1;           // 0..1 -> 32 cols
    const int l15  = lane & 15;
    const int lg   = lane >> 4;         // 0..3

    // --- staging sources (K-invariant, pre-swizzled) ---
    // X: 16 issues of 1KB = 8 rows x 128B. lane -> row j*8+(lane>>3),
    // 16B chunk (lane&7); source col chunk = (lane&7) ^ (row&7).
    const ushort* xsrc[4];
    // W: 16 issues of 1KB = 4 rows x 256B. lane -> row j*4+(lane>>4),
    // 16B chunk c16=lane&15; 32B chunk c32=c16>>1 swizzled by row&7.
    const float* w1src[4];
    const float* w3src[4];
    #pragma unroll
    for (int i = 0; i < 4; ++i) {
        const int j = wid*4 + i;
        const int rX = j*8 + (lane >> 3);
        const int cX = (lane & 7) ^ (rX & 7);
        xsrc[i] = xbf + (size_t)entry_token[off + ro + rX]*H_ + cX*8;
        const int rW = j*4 + (lane >> 4);
        const int c32 = ((lane & 15) >> 1) ^ (rW & 7);
        const int colW = c32*8 + (lane & 1)*4;
        w1src[i] = W1 + (size_t)(itile*BN + rW)*H_ + colW;
        w3src[i] = W3 + (size_t)(itile*BN + rW)*H_ + colW;
    }

    f32x4 acc1[4][2] = {};
    f32x4 acc3[4][2] = {};

    for (int t = 0; t < NT1; ++t) {
        const int kc = t * BKS;
        #pragma unroll
        for (int i = 0; i < 4; ++i)
            gload16(xsrc[i] + kc, (char*)XL + (wid*4 + i)*1024);
        #pragma unroll
        for (int i = 0; i < 4; ++i)
            gload16(w1src[i] + kc, (char*)W1L + (wid*4 + i)*1024);
        #pragma unroll
        for (int i = 0; i < 4; ++i)
            gload16(w3src[i] + kc, (char*)W3L + (wid*4 + i)*1024);
        __syncthreads();    // drain: tile ready
        #pragma unroll
        for (int s = 0; s < 2; ++s) {
            bf16x8 a[4];
            #pragma unroll
            for (int fm = 0; fm < 4; ++fm) {
                const int rr = wm*64 + fm*16 + l15;
                a[fm] = *reinterpret_cast<const bf16x8*>(
                    (const char*)XL + rr*128 + (((s*4 + lg) ^ (rr & 7)) << 4));
            }
            bf16x8 b1f[2], b3f[2];
            #pragma unroll
            for (int fn = 0; fn < 2; ++fn) {
                const int rw = wn*32 + fn*16 + l15;
                const int cw = ((s*4 + lg) ^ (rw & 7)) << 5;
                const char* p1 = (const char*)W1L + rw*256 + cw;
                b1f[fn] = cvt8(*reinterpret_cast<const f32x4*>(p1),
                               *reinterpret_cast<const f32x4*>(p1 + 16));
                const char* p3 = (const char*)W3L + rw*256 + cw;
                b3f[fn] = cvt8(*reinterpret_cast<const f32x4*>(p3),
                               *reinterpret_cast<const f32x4*>(p3 + 16));
            }
            #pragma unroll
            for (int fm = 0; fm < 4; ++fm) {
                #pragma unroll
                for (int fn = 0; fn < 2; ++fn) {
                    acc1[fm][fn] = __builtin_amdgcn_mfma_f32_16x16x32_bf16(a[fm], b1f[fn], acc1[fm][fn], 0, 0, 0);
                    acc3[fm][fn] = __builtin_amdgcn_mfma_f32_16x16x32_bf16(a[fm], b3f[fn], acc3[fm][fn], 0, 0, 0);
                }
            }
        }
        __syncthreads();    // readers done before next stage overwrites
    }

    // epilogue: silu(z1)*z3 -> bf16
    #pragma unroll
    for (int fm = 0; fm < 4; ++fm) {
        #pragma unroll
        for (int fn = 0; fn < 2; ++fn) {
            const int col = itile*BN + wn*32 + fn*16 + l15;
            const float bv1 = B1[col];
            const float bv3 = B3[col];
            #pragma unroll
            for (int j = 0; j < 4; ++j) {
                const int rl = wm*64 + fm*16 + lg*4 + j;   // C/D: row=(lane>>4)*4+reg, col=lane&15
                if (rl < rows) {
                    float z1 = acc1[fm][fn][j] + bv1;
                    float z3 = acc3[fm][fn][j] + bv3;
                    float h = z1 / (1.f + __expf(-z1)) * z3;
                    h1buf[(size_t)(off+ro+rl)*I_ + col] = f2bf(h);
                }
            }
        }
    }
}

// ---------------------------------------------------------------------------
// Stage 2: y = gate * (h1 @ w2^T + b2) -> fp32. Same m97 structure.
// H bf16 [128][64] + W2 fp32 [64][64] = 32 KB -> 4 blocks/CU.
// ---------------------------------------------------------------------------
__global__ __launch_bounds__(256, 4) void moe_stage2(
    const ushort* __restrict__ h1buf,
    const float* __restrict__ w2, const float* __restrict__ b2,
    const float* __restrict__ sw2, const float* __restrict__ sb2,
    const int* __restrict__ cnts, const int* __restrict__ offs,
    const float* __restrict__ entry_gate,
    const int* __restrict__ blk_e, const int* __restrict__ blk_ro,
    const int* __restrict__ nwork,
    float* __restrict__ ybuf)
{
    const int w = blockIdx.x;
    if (w >= nwork[0]) return;
    const int e  = blk_e[w];
    const int ro = blk_ro[w];
    const int htile = blockIdx.y;   // 0..H_/BN-1
    const int n = cnts[e];
    const int off = offs[e];
    const int rows = min(BM, n - ro);
    const float* W2 = (e < E_) ? (w2 + (size_t)e*H_*I_) : sw2;
    const float* B2 = (e < E_) ? (b2 + (size_t)e*H_) : sb2;

    __shared__ __align__(16) ushort HL [BM*BKS];   // 16 KB
    __shared__ __align__(16) float  W2L[BN*BKS];   // 16 KB

    const int tid  = threadIdx.x;
    const int lane = tid & 63;
    const int wid  = tid >> 6;          // 0..3
    const int wm   = wid >> 1;
    const int wn   = wid & 1;
    const int l15  = lane & 15;
    const int lg   = lane >> 4;

    const ushort* hsrc[4];
    const float*  wsrc[4];
    #pragma unroll
    for (int i = 0; i < 4; ++i) {
        const int j = wid*4 + i;
        const int rH = j*8 + (lane >> 3);
        const int cH = (lane & 7) ^ (rH & 7);
        hsrc[i] = h1buf + (size_t)(off + ro + rH)*I_ + cH*8;
        const int rW = j*4 + (lane >> 4);
        const int c32 = ((lane & 15) >> 1) ^ (rW & 7);
        wsrc[i] = W2 + (size_t)(htile*BN + rW)*I_ + c32*8 + (lane & 1)*4;
    }

    f32x4 acc[4][2] = {};

    for (int t = 0; t < NT2; ++t) {
        const int kc = t * BKS;
        #pragma unroll
        for (int i = 0; i < 4; ++i)
            gload16(hsrc[i] + kc, (char*)HL + (wid*4 + i)*1024);
        #pragma unroll
        for (int i = 0; i < 4; ++i)
            gload16(wsrc[i] + kc, (char*)W2L + (wid*4 + i)*1024);
        __syncthreads();
        #pragma unroll
        for (int s = 0; s < 2; ++s) {
            bf16x8 a[4];
            #pragma unroll
            for (int fm = 0; fm < 4; ++fm) {
                const int rr = wm*64 + fm*16 + l15;
                a[fm] = *reinterpret_cast<const bf16x8*>(
                    (const char*)HL + rr*128 + (((s*4 + lg) ^ (rr & 7)) << 4));
            }
            bf16x8 bf[2];
            #pragma unroll
            for (int fn = 0; fn < 2; ++fn) {
                const int rw = wn*32 + fn*16 + l15;
                const char* p = (const char*)W2L + rw*256 + (((s*4 + lg) ^ (rw & 7)) << 5);
                bf[fn] = cvt8(*reinterpret_cast<const f32x4*>(p),
                              *reinterpret_cast<const f32x4*>(p + 16));
            }
            #pragma unroll
            for (int fm = 0; fm < 4; ++fm) {
                #pragma unroll
                for (int fn = 0; fn < 2; ++fn) {
                    acc[fm][fn] = __builtin_amdgcn_mfma_f32_16x16x32_bf16(a[fm], bf[fn], acc[fm][fn], 0, 0, 0);
                }
            }
        }
        __syncthreads();
    }

    #pragma unroll
    for (int fm = 0; fm < 4; ++fm) {
        #pragma unroll
        for (int fn = 0; fn < 2; ++fn) {
            const int col = htile*BN + wn*32 + fn*16 + l15;
            const float bv = B2[col];
            #pragma unroll
            for (int j = 0; j < 4; ++j) {
                const int rl = wm*64 + fm*16 + lg*4 + j;
                if (rl < rows) {
                    const float g = entry_gate[off + ro + rl];
                    ybuf[(size_t)(off+ro+rl)*H_ + col] = (acc[fm][fn][j] + bv) * g;
                }
            }
        }
    }
}

// ---------------------------------------------------------------------------
// Combine: out[t] = y_shared[t] + sum_k y_routed[pair_pos[t,k]]
// ---------------------------------------------------------------------------
__global__ __launch_bounds__(128) void moe_combine(
    const float* __restrict__ ybuf, const int* __restrict__ pair_pos,
    float* __restrict__ out)
{
    const int t = blockIdx.x;
    const int lane = threadIdx.x;     // 128 threads * 4 floats = 512
    const int h = lane * 4;
    const int p0 = pair_pos[t*K_+0], p1 = pair_pos[t*K_+1];
    const int p2 = pair_pos[t*K_+2], p3 = pair_pos[t*K_+3];
    float4 a  = *reinterpret_cast<const float4*>(ybuf + (size_t)(NPAIR+t)*H_ + h);
    float4 v0 = *reinterpret_cast<const float4*>(ybuf + (size_t)p0*H_ + h);
    float4 v1 = *reinterpret_cast<const float4*>(ybuf + (size_t)p1*H_ + h);
    float4 v2 = *reinterpret_cast<const float4*>(ybuf + (size_t)p2*H_ + h);
    float4 v3 = *reinterpret_cast<const float4*>(ybuf + (size_t)p3*H_ + h);
    float4 r;
    r.x = a.x + v0.x + v1.x + v2.x + v3.x;
    r.y = a.y + v0.y + v1.y + v2.y + v3.y;
    r.z = a.z + v0.z + v1.z + v2.z + v3.z;
    r.w = a.w + v0.w + v1.w + v2.w + v3.w;
    *reinterpret_cast<float4*>(out + (size_t)t*H_ + h) = r;
}

extern "C" void kernel_launch(void* const* d_in, const int* in_sizes, int n_in,
                              void* d_out, int out_size, void* d_ws, size_t ws_size,
                              hipStream_t stream)
{
    const float* x   = (const float*)d_in[0];
    const float* rw  = (const float*)d_in[1];
    const float* rb  = (const float*)d_in[2];
    const float* eb  = (const float*)d_in[3];
    const float* sw1 = (const float*)d_in[4];
    const float* sb1 = (const float*)d_in[5];
    const float* sw2 = (const float*)d_in[6];
    const float* sb2 = (const float*)d_in[7];
    const float* sw3 = (const float*)d_in[8];
    const float* sb3 = (const float*)d_in[9];
    const float* w1  = (const float*)d_in[10];
    const float* b1  = (const float*)d_in[11];
    const float* w2  = (const float*)d_in[12];
    const float* b2  = (const float*)d_in[13];
    const float* w3  = (const float*)d_in[14];
    const float* b3  = (const float*)d_in[15];
    float* out = (float*)d_out;

    char* p = (char*)d_ws;
    auto take = [&](size_t bytes) { char* q = p; p += (bytes + 255) & ~(size_t)255; return q; };
    int*    idxb  = (int*)   take((size_t)NPAIR*4);
    float*  gateb = (float*) take((size_t)NPAIR*4);
    int*    cnts  = (int*)   take((E_+1)*4);
    int*    offs  = (int*)   take((E_+1)*4);
    int*    etok  = (int*)   take((size_t)NENT*4);
    float*  egate = (float*) take((size_t)NENT*4);
    int*    ppos  = (int*)   take((size_t)NPAIR*4);
    int*    blk_e = (int*)   take((size_t)MAXWORK*4);
    int*    blk_ro= (int*)   take((size_t)MAXWORK*4);
    int*    nwork = (int*)   take(4);
    ushort* xbf   = (ushort*)take((size_t)T_*H_*2);
    ushort* h1buf = (ushort*)take((size_t)NENT*I_*2);
    float*  ybuf  = (float*) take((size_t)NENT*H_*4);

    x_cvt      <<<(T_*H_)/(256*4), 256, 0, stream>>>(x, xbf);
    moe_router <<<T_, 64, 0, stream>>>(x, rw, rb, eb, idxb, gateb);
    moe_build  <<<1, 256, 0, stream>>>(idxb, gateb, cnts, offs, etok, egate, ppos,
                                       blk_e, blk_ro, nwork);
    moe_stage1 <<<dim3(MAXWORK, I_/BN), 256, 0, stream>>>(xbf, w1, b1, w3, b3,
                                                          sw1, sb1, sw3, sb3,
                                                          cnts, offs, etok,
                                                          blk_e, blk_ro, nwork, h1buf);
    moe_stage2 <<<dim3(MAXWORK, H_/BN), 256, 0, stream>>>(h1buf, w2, b2, sw2, sb2,
                                                          cnts, offs, egate,
                                                          blk_e, blk_ro, nwork, ybuf);
    moe_combine<<<T_, 128, 0, stream>>>(ybuf, ppos, out);
}